// Round 6
// baseline (6039.894 us; speedup 1.0000x reference)
//
#include <hip/hip_runtime.h>

#define NB 512
#define NL 512
#define NK 103
#define NH 512
#define NI 105
#define XROW (NL * NK)

typedef _Float16 half8 __attribute__((ext_vector_type(8)));
typedef _Float16 half4 __attribute__((ext_vector_type(4)));
typedef float floatx4 __attribute__((ext_vector_type(4)));
typedef unsigned int uint32x4 __attribute__((ext_vector_type(4)));

// LDS layout (bytes)
#define XB_STR 136
#define B2_STR 136
#define YST_STR 72
#define Y2_STR 16
#define OFF_XB   0        // 2 x 64 x 136 halves = 34816
#define OFF_B2   34816    // 17408
#define OFF_YST  52224    // 9216
#define OFF_Y2   61440    // 2048 (aliased as HTX after mid-step sync)
#define OFF_FR   63488    // 448 floats = 1792
#define OFF_TILE 65280    // 65536: h_{t-1} tile, fragment-major
#define SMEM_BYTES 130816

#define GBUF  524288      // per-parity hbuf (8 groups x 64KB)
#define GTILE 65536

#define SPIN_MAX (1 << 20)

#define A_LOAD(p)  __hip_atomic_load((p),  __ATOMIC_RELAXED, __HIP_MEMORY_SCOPE_AGENT)
#define A_STORE(p, v) __hip_atomic_store((p), (v), __ATOMIC_RELAXED, __HIP_MEMORY_SCOPE_AGENT)

// ws map: [0,4096) flags[8][32] spaced 4 dwords;
// [4096, +2*GBUF) hbuf double buffer, fragment-major per group:
//   off = par*GBUF + g*GTILE + kk*4096 + rb*1024 + (row&15)*64 + q*16 + j*2
//   holding h[row=16*rb+(row&15)][k=kk*32+q*8+j] as f16 — identical to the
//   LDS tile layout, so staging is a linear 16B/lane stream and the
//   coalesced 8B publish (4 cols/lane) lands contiguously.
// ALL cross-block traffic uses agent-scope atomics (the baseline's proven
// primitives). The sc0/XCD-local fast path (rounds 4-5) produced
// deterministic stale reads and is parked pending a verified probe.

__device__ __forceinline__ float fast_sigmoid(float v) {
  v = fminf(fmaxf(v, -30.f), 30.f);
  return __builtin_amdgcn_rcpf(1.f + __expf(-v));
}
__device__ __forceinline__ float fast_tanh(float v) {
  v = fminf(fmaxf(v, -15.f), 15.f);
  float e = __expf(-2.f * v);
  return (1.f - e) * __builtin_amdgcn_rcpf(1.f + e);
}

__global__ void __launch_bounds__(256, 1)
lstm_persist(const float* __restrict__ x, const float* __restrict__ pos,
             const float* __restrict__ h0, const float* __restrict__ c0,
             const float* __restrict__ Wih, const float* __restrict__ Whh,
             const float* __restrict__ bih, const float* __restrict__ bhh,
             const float* __restrict__ W1, const float* __restrict__ b1,
             const float* __restrict__ W2, const float* __restrict__ b2,
             const float* __restrict__ W3, const float* __restrict__ b3,
             float* __restrict__ out, void* __restrict__ ws)
{
  extern __shared__ char smem[];
  _Float16* B2s = (_Float16*)(smem + OFF_B2);
  _Float16* YST = (_Float16*)(smem + OFF_YST);
  _Float16* Y2  = (_Float16*)(smem + OFF_Y2);
  _Float16* HTX = Y2;   // reuse: Y2 dead before HTX writes begin
  float* FR  = (float*)(smem + OFF_FR);
  float* b1s = FR;          // 64
  float* b2s = FR + 64;     // 16
  float* w3s = FR + 80;     // 32
  float* b3s = FR + 112;    // 2
  float* wy0 = FR + 114;    // 64
  float* wy1 = FR + 178;    // 64
  float* bgs = FR + 242;    // 64
  float* ypres = FR + 306;  // 128
  volatile int* abflag = (volatile int*)(FR + 440);

  const int tid = threadIdx.x;
  const int g  = blockIdx.x & 7;    // batch group: rows 64g..64g+63
  const int cs = blockIdx.x >> 3;   // h-column slice: 16cs..16cs+15
  const int w  = tid >> 6, l = tid & 63;
  const int c16 = l & 15, q = l >> 4;
  const int rh = w >> 1;            // row half (32 rows)
  const int ch = w & 1;             // 0 = gates, 1 = MLP(W1)

  unsigned* flags = (unsigned*)ws;
  char* hbase = (char*)ws + 4096;
  char* tilebase = smem + OFF_TILE;

  if (tid == 0) *abflag = 0;

  // ---- zero xbuf (incl. zero-pad cols 103..127) ----
  {
    unsigned* xz = (unsigned*)(smem + OFF_XB);
    for (int i = tid; i < 8704; i += 256) xz[i] = 0;
  }
  // ---- W_ih x-part -> LDS fp16 ----
  for (int idx = tid; idx < 64 * 128; idx += 256) {
    int cc = idx >> 7, k = idx & 127;
    int gr = (cc >> 4) * NH + cs * 16 + (cc & 15);
    float v = (k < NK) ? Wih[(size_t)gr * NI + k] : 0.f;
    B2s[cc * B2_STR + k] = (_Float16)v;
  }
  // ---- small fp32 tables ----
  if (tid < 64) {
    int gr = (tid >> 4) * NH + cs * 16 + (tid & 15);
    wy0[tid] = Wih[(size_t)gr * NI + 103];
    wy1[tid] = Wih[(size_t)gr * NI + 104];
    bgs[tid] = bih[gr] + bhh[gr];
    b1s[tid] = b1[tid];
  }
  if (tid < 16) b2s[tid] = b2[tid];
  if (tid < 32) w3s[tid] = W3[tid];
  if (tid < 2)  b3s[tid] = b3[tid];

  // ---- h0 -> hbuf[0] (fragment-major), agent-scope 8B stores ----
  {
    const int r = tid >> 2, hb = tid & 3;
    const float* src = h0 + (size_t)(64 * g + r) * NH + cs * 16 + hb * 4;
    union { unsigned long long u; half4 h; } cv;
    cv.h[0] = (_Float16)src[0]; cv.h[1] = (_Float16)src[1];
    cv.h[2] = (_Float16)src[2]; cv.h[3] = (_Float16)src[3];
    char* dst = hbase + (size_t)g * GTILE + (size_t)(cs >> 1) * 4096
              + (size_t)(r >> 4) * 1024 + (size_t)(r & 15) * 64
              + (size_t)((cs & 1) * 2 + (hb >> 1)) * 16 + (size_t)(hb & 1) * 8;
    A_STORE((unsigned long long*)dst, cv.u);
  }

  // ---- B weight fragments -> registers (held all 512 steps) ----
  half8 bfr[4][16];
  #pragma unroll
  for (int ct = 0; ct < 4; ++ct) {
    const int rown = ch ? (ct * 16 + c16) : (ct * NH + cs * 16 + c16);
    const float* rp = (ch ? W1 : Whh) + (size_t)rown * NH;
    #pragma unroll
    for (int kk = 0; kk < 16; ++kk) {
      const float* p = rp + kk * 32 + q * 8;
      floatx4 f0 = *(const floatx4*)(p);
      floatx4 f1 = *(const floatx4*)(p + 4);
      half8 hv;
      hv[0]=(_Float16)f0[0]; hv[1]=(_Float16)f0[1]; hv[2]=(_Float16)f0[2]; hv[3]=(_Float16)f0[3];
      hv[4]=(_Float16)f1[0]; hv[5]=(_Float16)f1[1]; hv[6]=(_Float16)f1[2]; hv[7]=(_Float16)f1[3];
      bfr[ct][kk] = hv;
    }
  }
  half8 w2f[2];
  if (ch) {
    #pragma unroll
    for (int kk = 0; kk < 2; ++kk) {
      const float* p = W2 + c16 * 64 + kk * 32 + q * 8;
      floatx4 f0 = *(const floatx4*)(p);
      floatx4 f1 = *(const floatx4*)(p + 4);
      half8 hv;
      hv[0]=(_Float16)f0[0]; hv[1]=(_Float16)f0[1]; hv[2]=(_Float16)f0[2]; hv[3]=(_Float16)f0[3];
      hv[4]=(_Float16)f1[0]; hv[5]=(_Float16)f1[1]; hv[6]=(_Float16)f1[2]; hv[7]=(_Float16)f1[3];
      w2f[kk] = hv;
    }
  }
  float cacc[2][4];
  if (!ch) {
    #pragma unroll
    for (int rt = 0; rt < 2; ++rt)
      #pragma unroll
      for (int reg = 0; reg < 4; ++reg)
        cacc[rt][reg] = c0[(size_t)(64 * g + 32 * rh + 16 * rt + q * 4 + reg) * NH + cs * 16 + c16];
  }

  // coalesced x_t -> LDS f16 stager (gate waves; 2 lanes per row)
  auto xstage = [&](int t1) {
    _Float16* xb = (_Float16*)(smem + OFF_XB) + (size_t)(t1 & 1) * 64 * XB_STR;
    const int row = 32 * rh + (l >> 1);
    const int p = l & 1;
    const float* src = x + (size_t)(64 * g + row) * XROW + (size_t)t1 * NK + p * 52;
    _Float16* dst = xb + row * XB_STR + p * 52;
    const int nfull = p ? 12 : 13;
    for (int cnk = 0; cnk < nfull; ++cnk) {
      float f0 = src[cnk * 4 + 0], f1 = src[cnk * 4 + 1];
      float f2 = src[cnk * 4 + 2], f3 = src[cnk * 4 + 3];
      half4 hv; hv[0]=(_Float16)f0; hv[1]=(_Float16)f1; hv[2]=(_Float16)f2; hv[3]=(_Float16)f3;
      *(half4*)(dst + cnk * 4) = hv;
    }
    if (p) {
      dst[48] = (_Float16)src[48];
      dst[49] = (_Float16)src[49];
      dst[50] = (_Float16)src[50];
    }
  };

  __syncthreads();          // init LDS + h0 stores drained (barrier waits vmcnt)
  if (!ch) xstage(0);       // x_0 -> xbuf[0]
  __syncthreads();
  if (tid == 0) A_STORE(flags + ((g << 5) + cs) * 4, 1u);   // h0 published

  for (int t = 0; t <= NL; ++t) {
    // ---- per-wave poll: all 32 producers of this step's tile ----
    if (l < 32) {
      const unsigned* f = flags + ((g << 5) + l) * 4;
      int spins = 0;
      while (A_LOAD(f) < (unsigned)(t + 1)) {
        if (++spins > SPIN_MAX) { *abflag = 1; break; }
      }
    }

    // ---- issue tile loads (16 x 16B/lane, agent scope; block stages once) ----
    union { uint32x4 v; unsigned long long u[2]; } stg[16];
    {
      const char* sb = hbase + (size_t)(t & 1) * GBUF + (size_t)g * GTILE
                     + (size_t)(w * 1024) + (size_t)(l * 16);
      #pragma unroll
      for (int i = 0; i < 16; ++i) {
        const unsigned long long* sp = (const unsigned long long*)(sb + i * 4096);
        stg[i].u[0] = A_LOAD(sp);
        stg[i].u[1] = A_LOAD(sp + 1);
      }
    }

    floatx4 acc[4][2] = {};

    // ---- phase 2 (gate waves): x_t part — overlaps the in-flight tile loads ----
    if (!ch && t < NL) {
      const _Float16* xb = (const _Float16*)(smem + OFF_XB) + (size_t)(t & 1) * 64 * XB_STR;
      #pragma unroll
      for (int kb = 0; kb < 4; ++kb) {
        half8 ax[2];
        #pragma unroll
        for (int rt = 0; rt < 2; ++rt)
          ax[rt] = *(const half8*)(xb + (32 * rh + 16 * rt + c16) * XB_STR + kb * 32 + q * 8);
        #pragma unroll
        for (int ct = 0; ct < 4; ++ct) {
          half8 bf = *(const half8*)(B2s + (ct * 16 + c16) * B2_STR + kb * 32 + q * 8);
          #pragma unroll
          for (int rt = 0; rt < 2; ++rt)
            acc[ct][rt] = __builtin_amdgcn_mfma_f32_16x16x32_f16(ax[rt], bf, acc[ct][rt], 0, 0, 0);
        }
      }
      if (t + 1 < NL) xstage(t + 1);
    }

    // ---- write staged tile to LDS (compiler inserts waitcnt on stg deps) ----
    {
      char* dl = tilebase + w * 1024 + l * 16;
      #pragma unroll
      for (int i = 0; i < 16; ++i)
        *(uint32x4*)(dl + i * 4096) = stg[i].v;
    }
    __syncthreads();    // tile staged & visible to all waves

    // ---- phase 1: K=512 over h_{t-1}; A from LDS tile (1KB/wave linear reads) ----
    if (ch || t < NL) {
      const char* tb = tilebase + (size_t)rh * 2048 + (size_t)c16 * 64 + (size_t)q * 16;
      #pragma unroll
      for (int kk = 0; kk < 16; ++kk) {
        half8 a0 = *(const half8*)(tb + kk * 4096);
        half8 a1 = *(const half8*)(tb + kk * 4096 + 1024);
        #pragma unroll
        for (int ct = 0; ct < 4; ++ct) {
          acc[ct][0] = __builtin_amdgcn_mfma_f32_16x16x32_f16(a0, bfr[ct][kk], acc[ct][0], 0, 0, 0);
          acc[ct][1] = __builtin_amdgcn_mfma_f32_16x16x32_f16(a1, bfr[ct][kk], acc[ct][1], 0, 0, 0);
        }
      }
    }

    // ---- MLP waves: y_{t-1} (or pos init at t==0) ----
    if (ch) {
      if (t == 0) {
        if (l < 32) {
          int row = 32 * rh + l;
          const float* pp = pos + (size_t)(64 * g + row) * (NL * 2);
          ypres[row * 2 + 0] = pp[0];
          ypres[row * 2 + 1] = pp[1];
        }
      } else {
        #pragma unroll
        for (int ct = 0; ct < 4; ++ct)
          #pragma unroll
          for (int rt = 0; rt < 2; ++rt)
            #pragma unroll
            for (int reg = 0; reg < 4; ++reg) {
              int row = 32 * rh + 16 * rt + q * 4 + reg;
              float v = acc[ct][rt][reg] + b1s[ct * 16 + c16];
              YST[row * YST_STR + ct * 16 + c16] = (_Float16)fmaxf(v, 0.f);
            }
        floatx4 a2c[2] = {};
        #pragma unroll
        for (int kk2 = 0; kk2 < 2; ++kk2)
          #pragma unroll
          for (int rt = 0; rt < 2; ++rt) {
            half8 af = *(const half8*)(YST + (32 * rh + 16 * rt + c16) * YST_STR + kk2 * 32 + q * 8);
            a2c[rt] = __builtin_amdgcn_mfma_f32_16x16x32_f16(af, w2f[kk2], a2c[rt], 0, 0, 0);
          }
        #pragma unroll
        for (int rt = 0; rt < 2; ++rt)
          #pragma unroll
          for (int reg = 0; reg < 4; ++reg) {
            int row = 32 * rh + 16 * rt + q * 4 + reg;
            float v = a2c[rt][reg] + b2s[c16];
            Y2[row * Y2_STR + c16] = (_Float16)fmaxf(v, 0.f);
          }
        if (l < 32) {
          int row = 32 * rh + l;
          float y0 = b3s[0], y1 = b3s[1];
          #pragma unroll
          for (int k = 0; k < 16; ++k) {
            float vv = (float)Y2[row * Y2_STR + k];
            y0 += vv * w3s[k];
            y1 += vv * w3s[16 + k];
          }
          y0 = fmaxf(y0, 0.f); y1 = fmaxf(y1, 0.f);
          ypres[row * 2 + 0] = y0;
          ypres[row * 2 + 1] = y1;
          if (cs == 0) {
            float2* op = (float2*)(out + (size_t)(64 * g + row) * (NL * 2) + (size_t)(t - 1) * 2);
            *op = make_float2(y0, y1);
          }
        }
      }
    }
    __syncthreads();        // ypres ready; Y2 reads done (HTX may overwrite)
    if (*abflag) return;    // uniform abort point

    // ---- gate epilogue: feedback + bias + LSTM cell; h_t -> HTX tile ----
    if (!ch && t < NL) {
      #pragma unroll
      for (int rt = 0; rt < 2; ++rt)
        #pragma unroll
        for (int reg = 0; reg < 4; ++reg) {
          int rl = 32 * rh + 16 * rt + q * 4 + reg;
          float yp0 = ypres[rl * 2], yp1 = ypres[rl * 2 + 1];
          float gi = acc[0][rt][reg] + bgs[c16]      + yp0 * wy0[c16]      + yp1 * wy1[c16];
          float gf = acc[1][rt][reg] + bgs[16 + c16] + yp0 * wy0[16 + c16] + yp1 * wy1[16 + c16];
          float gg = acc[2][rt][reg] + bgs[32 + c16] + yp0 * wy0[32 + c16] + yp1 * wy1[32 + c16];
          float go = acc[3][rt][reg] + bgs[48 + c16] + yp0 * wy0[48 + c16] + yp1 * wy1[48 + c16];
          float iv = fast_sigmoid(gi);
          float fv = fast_sigmoid(gf);
          float gv = fast_tanh(gg);
          float ov = fast_sigmoid(go);
          float cn = fv * cacc[rt][reg] + iv * gv;
          cacc[rt][reg] = cn;
          float hn = ov * fast_tanh(cn);
          HTX[rl * 16 + c16] = (_Float16)hn;
          if (t == NL - 1) {
            out[(size_t)(NB * NL * 2) + (size_t)(64 * g + rl) * NH + cs * 16 + c16] = hn;
            out[(size_t)(NB * NL * 2) + (size_t)(NB * NH) + (size_t)(64 * g + rl) * NH + cs * 16 + c16] = cn;
          }
        }
    }

    if (t < NL) {
      __syncthreads();  // HTX complete
      // publish h_t: 256 threads x 8B agent stores, fragment-major
      {
        const int r = tid >> 2, hb = tid & 3;
        char* dst = hbase + (size_t)((t + 1) & 1) * GBUF + (size_t)g * GTILE
                  + (size_t)(cs >> 1) * 4096
                  + (size_t)(r >> 4) * 1024 + (size_t)(r & 15) * 64
                  + (size_t)((cs & 1) * 2 + (hb >> 1)) * 16 + (size_t)(hb & 1) * 8;
        unsigned long long v = *(const unsigned long long*)(HTX + r * 16 + hb * 4);
        A_STORE((unsigned long long*)dst, v);
      }
      __syncthreads();          // drain publishes (vmcnt 0 in every wave)
      if (tid == 0) A_STORE(flags + ((g << 5) + cs) * 4, (unsigned)(t + 2));
    }
  }
}

extern "C" void kernel_launch(void* const* d_in, const int* in_sizes, int n_in,
                              void* d_out, int out_size, void* d_ws, size_t ws_size,
                              hipStream_t stream) {
  (void)in_sizes; (void)n_in; (void)out_size; (void)ws_size;
  const float* x   = (const float*)d_in[0];
  const float* pos = (const float*)d_in[1];
  const float* h0  = (const float*)d_in[2];
  const float* c0  = (const float*)d_in[3];
  const float* Wih = (const float*)d_in[4];
  const float* Whh = (const float*)d_in[5];
  const float* bih = (const float*)d_in[6];
  const float* bhh = (const float*)d_in[7];
  const float* W1  = (const float*)d_in[8];
  const float* b1  = (const float*)d_in[9];
  const float* W2  = (const float*)d_in[10];
  const float* b2  = (const float*)d_in[11];
  const float* W3  = (const float*)d_in[12];
  const float* b3  = (const float*)d_in[13];
  float* out = (float*)d_out;

  static bool smem_attr_set = false;
  if (!smem_attr_set) {
    (void)hipFuncSetAttribute(reinterpret_cast<const void*>(lstm_persist),
                              hipFuncAttributeMaxDynamicSharedMemorySize, SMEM_BYTES);
    smem_attr_set = true;
  }

  hipMemsetAsync(d_ws, 0, 4096, stream);  // flags

  void* args[] = { (void*)&x, (void*)&pos, (void*)&h0, (void*)&c0,
                   (void*)&Wih, (void*)&Whh, (void*)&bih, (void*)&bhh,
                   (void*)&W1, (void*)&b1, (void*)&W2, (void*)&b2,
                   (void*)&W3, (void*)&b3, (void*)&out, (void*)&d_ws };

  hipError_t err = hipLaunchCooperativeKernel(
      reinterpret_cast<void*>(lstm_persist),
      dim3(256, 1, 1), dim3(256, 1, 1), args, (unsigned)SMEM_BYTES, stream);
  if (err != hipSuccess) {
    (void)hipGetLastError();
    lstm_persist<<<dim3(256, 1, 1), dim3(256, 1, 1), SMEM_BYTES, stream>>>(
        x, pos, h0, c0, Wih, Whh, bih, bhh, W1, b1, W2, b2, W3, b3, out, d_ws);
  }
}

// Round 7
// 5458.428 us; speedup vs baseline: 1.1065x; 1.1065x over previous
//
#include <hip/hip_runtime.h>

#define NB 512
#define NL 512
#define NK 103
#define NH 512
#define NI 105
#define XROW (NL * NK)

typedef _Float16 half8 __attribute__((ext_vector_type(8)));
typedef _Float16 half4 __attribute__((ext_vector_type(4)));
typedef float floatx4 __attribute__((ext_vector_type(4)));

union U16 { half8 h; unsigned long long u[2]; };

// LDS layout (bytes)
#define XB_STR 136
#define B2_STR 136
#define YST_STR 72
#define Y2_STR 16
#define OFF_XB  0             // 2 x 64 x 136 halves = 34816
#define OFF_B2  34816         // 17408
#define OFF_YST 52224         // 9216
#define OFF_Y2  61440         // 2048 (aliased as HTX after mid-step sync)
#define OFF_FR  63488         // 448 floats
#define SMEM_BYTES 65280

#define GBUF  524288      // per-parity hbuf (8 groups x 64KB)
#define GTILE 65536

#define SPIN_MAX (1 << 20)

#define A_LOAD(p)  __hip_atomic_load((p),  __ATOMIC_RELAXED, __HIP_MEMORY_SCOPE_AGENT)
#define A_STORE(p, v) __hip_atomic_store((p), (v), __ATOMIC_RELAXED, __HIP_MEMORY_SCOPE_AGENT)

// ws map: [0,4096) per-group publish counters cnt[g] at dword g*16 (64B
// spacing). Producers fetch_add(1) after a vmcnt-drained publish; consumers
// poll ONE line per wave (all lanes same addr) for cnt >= 32*(t+1) — replaces
// the 32-flag scan (8 lines/wave/iteration poll storm).
// [4096, +2*GBUF) hbuf double buffer, fragment-major per group:
//   off = par*GBUF + g*GTILE + kk*4096 + rb*1024 + (row&15)*64 + q*16 + j*2
//   holding h[row=16*rb+(row&15)][k=kk*32+q*8+j] as f16 — per-lane 16B
//   contiguous for the reg-fed A loads; the 8B publish lands contiguously
//   (2KB/block), avoiding RMW line fetches (round-6 verified layout).
// Phase-1 A operands load straight to registers (two 8B agent loads per
// fragment, baseline-proven): no LDS tile, no stage barrier, no 8-way
// bank-conflicted tile reads (round-6 regression: +657us).
// All cross-block traffic stays agent-scope (sc0 fast path parked: rounds
// 4-5 showed deterministic stale reads).

__device__ __forceinline__ float fast_sigmoid(float v) {
  v = fminf(fmaxf(v, -30.f), 30.f);
  return __builtin_amdgcn_rcpf(1.f + __expf(-v));
}
__device__ __forceinline__ float fast_tanh(float v) {
  v = fminf(fmaxf(v, -15.f), 15.f);
  float e = __expf(-2.f * v);
  return (1.f - e) * __builtin_amdgcn_rcpf(1.f + e);
}

__global__ void __launch_bounds__(256, 1)
lstm_persist(const float* __restrict__ x, const float* __restrict__ pos,
             const float* __restrict__ h0, const float* __restrict__ c0,
             const float* __restrict__ Wih, const float* __restrict__ Whh,
             const float* __restrict__ bih, const float* __restrict__ bhh,
             const float* __restrict__ W1, const float* __restrict__ b1,
             const float* __restrict__ W2, const float* __restrict__ b2,
             const float* __restrict__ W3, const float* __restrict__ b3,
             float* __restrict__ out, void* __restrict__ ws)
{
  extern __shared__ char smem[];
  _Float16* B2s = (_Float16*)(smem + OFF_B2);
  _Float16* YST = (_Float16*)(smem + OFF_YST);
  _Float16* Y2  = (_Float16*)(smem + OFF_Y2);
  _Float16* HTX = Y2;   // reuse: Y2 dead before HTX writes begin
  float* FR  = (float*)(smem + OFF_FR);
  float* b1s = FR;          // 64
  float* b2s = FR + 64;     // 16
  float* w3s = FR + 80;     // 32
  float* b3s = FR + 112;    // 2
  float* wy0 = FR + 114;    // 64
  float* wy1 = FR + 178;    // 64
  float* bgs = FR + 242;    // 64
  float* ypres = FR + 306;  // 128
  volatile int* abflag = (volatile int*)(FR + 440);

  const int tid = threadIdx.x;
  const int g  = blockIdx.x & 7;    // batch group: rows 64g..64g+63
  const int cs = blockIdx.x >> 3;   // h-column slice: 16cs..16cs+15
  const int w  = tid >> 6, l = tid & 63;
  const int c16 = l & 15, q = l >> 4;
  const int rh = w >> 1;            // row half (32 rows)
  const int ch = w & 1;             // 0 = gates, 1 = MLP(W1)

  unsigned* cnt = (unsigned*)ws + (size_t)g * 16;   // 64B-spaced group counter
  char* hbase = (char*)ws + 4096;

  if (tid == 0) *abflag = 0;

  // ---- zero xbuf (incl. zero-pad cols 103..127) ----
  {
    unsigned* xz = (unsigned*)(smem + OFF_XB);
    for (int i = tid; i < 8704; i += 256) xz[i] = 0;
  }
  // ---- W_ih x-part -> LDS fp16 ----
  for (int idx = tid; idx < 64 * 128; idx += 256) {
    int cc = idx >> 7, k = idx & 127;
    int gr = (cc >> 4) * NH + cs * 16 + (cc & 15);
    float v = (k < NK) ? Wih[(size_t)gr * NI + k] : 0.f;
    B2s[cc * B2_STR + k] = (_Float16)v;
  }
  // ---- small fp32 tables ----
  if (tid < 64) {
    int gr = (tid >> 4) * NH + cs * 16 + (tid & 15);
    wy0[tid] = Wih[(size_t)gr * NI + 103];
    wy1[tid] = Wih[(size_t)gr * NI + 104];
    bgs[tid] = bih[gr] + bhh[gr];
    b1s[tid] = b1[tid];
  }
  if (tid < 16) b2s[tid] = b2[tid];
  if (tid < 32) w3s[tid] = W3[tid];
  if (tid < 2)  b3s[tid] = b3[tid];

  // ---- h0 -> hbuf[0] (fragment-major), agent-scope 8B stores ----
  {
    const int r = tid >> 2, hb = tid & 3;
    const float* src = h0 + (size_t)(64 * g + r) * NH + cs * 16 + hb * 4;
    union { unsigned long long u; half4 h; } cv;
    cv.h[0] = (_Float16)src[0]; cv.h[1] = (_Float16)src[1];
    cv.h[2] = (_Float16)src[2]; cv.h[3] = (_Float16)src[3];
    char* dst = hbase + (size_t)g * GTILE + (size_t)(cs >> 1) * 4096
              + (size_t)(r >> 4) * 1024 + (size_t)(r & 15) * 64
              + (size_t)((cs & 1) * 2 + (hb >> 1)) * 16 + (size_t)(hb & 1) * 8;
    A_STORE((unsigned long long*)dst, cv.u);
  }

  // ---- B weight fragments -> registers (held all 512 steps) ----
  half8 bfr[4][16];
  #pragma unroll
  for (int ct = 0; ct < 4; ++ct) {
    const int rown = ch ? (ct * 16 + c16) : (ct * NH + cs * 16 + c16);
    const float* rp = (ch ? W1 : Whh) + (size_t)rown * NH;
    #pragma unroll
    for (int kk = 0; kk < 16; ++kk) {
      const float* p = rp + kk * 32 + q * 8;
      floatx4 f0 = *(const floatx4*)(p);
      floatx4 f1 = *(const floatx4*)(p + 4);
      half8 hv;
      hv[0]=(_Float16)f0[0]; hv[1]=(_Float16)f0[1]; hv[2]=(_Float16)f0[2]; hv[3]=(_Float16)f0[3];
      hv[4]=(_Float16)f1[0]; hv[5]=(_Float16)f1[1]; hv[6]=(_Float16)f1[2]; hv[7]=(_Float16)f1[3];
      bfr[ct][kk] = hv;
    }
  }
  half8 w2f[2];
  if (ch) {
    #pragma unroll
    for (int kk = 0; kk < 2; ++kk) {
      const float* p = W2 + c16 * 64 + kk * 32 + q * 8;
      floatx4 f0 = *(const floatx4*)(p);
      floatx4 f1 = *(const floatx4*)(p + 4);
      half8 hv;
      hv[0]=(_Float16)f0[0]; hv[1]=(_Float16)f0[1]; hv[2]=(_Float16)f0[2]; hv[3]=(_Float16)f0[3];
      hv[4]=(_Float16)f1[0]; hv[5]=(_Float16)f1[1]; hv[6]=(_Float16)f1[2]; hv[7]=(_Float16)f1[3];
      w2f[kk] = hv;
    }
  }
  float cacc[2][4];
  if (!ch) {
    #pragma unroll
    for (int rt = 0; rt < 2; ++rt)
      #pragma unroll
      for (int reg = 0; reg < 4; ++reg)
        cacc[rt][reg] = c0[(size_t)(64 * g + 32 * rh + 16 * rt + q * 4 + reg) * NH + cs * 16 + c16];
  }

  // coalesced x_t -> LDS f16 stager (gate waves; 2 lanes per row)
  auto xstage = [&](int t1) {
    _Float16* xb = (_Float16*)(smem + OFF_XB) + (size_t)(t1 & 1) * 64 * XB_STR;
    const int row = 32 * rh + (l >> 1);
    const int p = l & 1;
    const float* src = x + (size_t)(64 * g + row) * XROW + (size_t)t1 * NK + p * 52;
    _Float16* dst = xb + row * XB_STR + p * 52;
    const int nfull = p ? 12 : 13;
    for (int cnk = 0; cnk < nfull; ++cnk) {
      float f0 = src[cnk * 4 + 0], f1 = src[cnk * 4 + 1];
      float f2 = src[cnk * 4 + 2], f3 = src[cnk * 4 + 3];
      half4 hv; hv[0]=(_Float16)f0; hv[1]=(_Float16)f1; hv[2]=(_Float16)f2; hv[3]=(_Float16)f3;
      *(half4*)(dst + cnk * 4) = hv;
    }
    if (p) {
      dst[48] = (_Float16)src[48];
      dst[49] = (_Float16)src[49];
      dst[50] = (_Float16)src[50];
    }
  };

  __syncthreads();          // init LDS + h0 stores drained (barrier waits vmcnt)
  if (!ch) xstage(0);       // x_0 -> xbuf[0]
  __syncthreads();
  if (tid == 0)             // h0 slice published -> bump group counter
    __hip_atomic_fetch_add(cnt, 1u, __ATOMIC_RELAXED, __HIP_MEMORY_SCOPE_AGENT);

  for (int t = 0; t <= NL; ++t) {
    // ---- poll the single group counter (all lanes same addr: 1 txn/wave) ----
    {
      const unsigned target = 32u * (unsigned)(t + 1);
      int spins = 0;
      while (A_LOAD(cnt) < target) {
        if (++spins > SPIN_MAX) { *abflag = 1; break; }
      }
    }

    // ---- issue all A-loads (fragment-major, 16B/lane contiguous, 64 x 8B) ----
    U16 ar[2][16];
    {
      const char* lb = hbase + (size_t)(t & 1) * GBUF + (size_t)g * GTILE
                     + (size_t)(2 * rh) * 1024 + (size_t)c16 * 64 + (size_t)q * 16;
      #pragma unroll
      for (int kk = 0; kk < 16; ++kk) {
        #pragma unroll
        for (int rt = 0; rt < 2; ++rt) {
          const unsigned long long* up =
              (const unsigned long long*)(lb + (size_t)kk * 4096 + rt * 1024);
          ar[rt][kk].u[0] = A_LOAD(up);
          ar[rt][kk].u[1] = A_LOAD(up + 1);
        }
      }
    }

    floatx4 acc[4][2] = {};

    // ---- phase 2 (gate waves): x_t from LDS — overlaps in-flight A-loads ----
    if (!ch && t < NL) {
      const _Float16* xb = (const _Float16*)(smem + OFF_XB) + (size_t)(t & 1) * 64 * XB_STR;
      #pragma unroll
      for (int kb = 0; kb < 4; ++kb) {
        half8 ax[2];
        #pragma unroll
        for (int rt = 0; rt < 2; ++rt)
          ax[rt] = *(const half8*)(xb + (32 * rh + 16 * rt + c16) * XB_STR + kb * 32 + q * 8);
        #pragma unroll
        for (int ct = 0; ct < 4; ++ct) {
          half8 bf = *(const half8*)(B2s + (ct * 16 + c16) * B2_STR + kb * 32 + q * 8);
          #pragma unroll
          for (int rt = 0; rt < 2; ++rt)
            acc[ct][rt] = __builtin_amdgcn_mfma_f32_16x16x32_f16(ax[rt], bf, acc[ct][rt], 0, 0, 0);
        }
      }
      if (t + 1 < NL) xstage(t + 1);
    }

    // ---- phase 1: K=512 over h_{t-1}; A from regs, B from regs ----
    #pragma unroll
    for (int kk = 0; kk < 16; ++kk)
      #pragma unroll
      for (int ct = 0; ct < 4; ++ct) {
        acc[ct][0] = __builtin_amdgcn_mfma_f32_16x16x32_f16(ar[0][kk].h, bfr[ct][kk], acc[ct][0], 0, 0, 0);
        acc[ct][1] = __builtin_amdgcn_mfma_f32_16x16x32_f16(ar[1][kk].h, bfr[ct][kk], acc[ct][1], 0, 0, 0);
      }

    // ---- MLP waves: y_{t-1} (or pos init at t==0) ----
    if (ch) {
      if (t == 0) {
        if (l < 32) {
          int row = 32 * rh + l;
          const float* pp = pos + (size_t)(64 * g + row) * (NL * 2);
          ypres[row * 2 + 0] = pp[0];
          ypres[row * 2 + 1] = pp[1];
        }
      } else {
        #pragma unroll
        for (int ct = 0; ct < 4; ++ct)
          #pragma unroll
          for (int rt = 0; rt < 2; ++rt)
            #pragma unroll
            for (int reg = 0; reg < 4; ++reg) {
              int row = 32 * rh + 16 * rt + q * 4 + reg;
              float v = acc[ct][rt][reg] + b1s[ct * 16 + c16];
              YST[row * YST_STR + ct * 16 + c16] = (_Float16)fmaxf(v, 0.f);
            }
        floatx4 a2c[2] = {};
        #pragma unroll
        for (int kk2 = 0; kk2 < 2; ++kk2)
          #pragma unroll
          for (int rt = 0; rt < 2; ++rt) {
            half8 af = *(const half8*)(YST + (32 * rh + 16 * rt + c16) * YST_STR + kk2 * 32 + q * 8);
            a2c[rt] = __builtin_amdgcn_mfma_f32_16x16x32_f16(af, w2f[kk2], a2c[rt], 0, 0, 0);
          }
        #pragma unroll
        for (int rt = 0; rt < 2; ++rt)
          #pragma unroll
          for (int reg = 0; reg < 4; ++reg) {
            int row = 32 * rh + 16 * rt + q * 4 + reg;
            float v = a2c[rt][reg] + b2s[c16];
            Y2[row * Y2_STR + c16] = (_Float16)fmaxf(v, 0.f);
          }
        if (l < 32) {
          int row = 32 * rh + l;
          float y0 = b3s[0], y1 = b3s[1];
          #pragma unroll
          for (int k = 0; k < 16; ++k) {
            float vv = (float)Y2[row * Y2_STR + k];
            y0 += vv * w3s[k];
            y1 += vv * w3s[16 + k];
          }
          y0 = fmaxf(y0, 0.f); y1 = fmaxf(y1, 0.f);
          ypres[row * 2 + 0] = y0;
          ypres[row * 2 + 1] = y1;
          if (cs == 0) {
            float2* op = (float2*)(out + (size_t)(64 * g + row) * (NL * 2) + (size_t)(t - 1) * 2);
            *op = make_float2(y0, y1);
          }
        }
      }
    }
    __syncthreads();        // ypres ready; Y2 reads done (HTX may overwrite)
    if (*abflag) return;    // uniform abort point

    // ---- gate epilogue: feedback + bias + LSTM cell; h_t -> HTX tile ----
    if (!ch && t < NL) {
      #pragma unroll
      for (int rt = 0; rt < 2; ++rt)
        #pragma unroll
        for (int reg = 0; reg < 4; ++reg) {
          int rl = 32 * rh + 16 * rt + q * 4 + reg;
          float yp0 = ypres[rl * 2], yp1 = ypres[rl * 2 + 1];
          float gi = acc[0][rt][reg] + bgs[c16]      + yp0 * wy0[c16]      + yp1 * wy1[c16];
          float gf = acc[1][rt][reg] + bgs[16 + c16] + yp0 * wy0[16 + c16] + yp1 * wy1[16 + c16];
          float gg = acc[2][rt][reg] + bgs[32 + c16] + yp0 * wy0[32 + c16] + yp1 * wy1[32 + c16];
          float go = acc[3][rt][reg] + bgs[48 + c16] + yp0 * wy0[48 + c16] + yp1 * wy1[48 + c16];
          float iv = fast_sigmoid(gi);
          float fv = fast_sigmoid(gf);
          float gv = fast_tanh(gg);
          float ov = fast_sigmoid(go);
          float cn = fv * cacc[rt][reg] + iv * gv;
          cacc[rt][reg] = cn;
          float hn = ov * fast_tanh(cn);
          HTX[rl * 16 + c16] = (_Float16)hn;
          if (t == NL - 1) {
            out[(size_t)(NB * NL * 2) + (size_t)(64 * g + rl) * NH + cs * 16 + c16] = hn;
            out[(size_t)(NB * NL * 2) + (size_t)(NB * NH) + (size_t)(64 * g + rl) * NH + cs * 16 + c16] = cn;
          }
        }
    }

    if (t < NL) {
      __syncthreads();  // HTX complete
      // publish h_t: 256 threads x 8B agent stores, fragment-major (2KB contig)
      {
        const int r = tid >> 2, hb = tid & 3;
        char* dst = hbase + (size_t)((t + 1) & 1) * GBUF + (size_t)g * GTILE
                  + (size_t)(cs >> 1) * 4096
                  + (size_t)(r >> 4) * 1024 + (size_t)(r & 15) * 64
                  + (size_t)((cs & 1) * 2 + (hb >> 1)) * 16 + (size_t)(hb & 1) * 8;
        unsigned long long v = *(const unsigned long long*)(HTX + r * 16 + hb * 4);
        A_STORE((unsigned long long*)dst, v);
      }
      __syncthreads();          // drain publishes (vmcnt 0 in every wave)
      if (tid == 0)             // bump group counter for step t+1 consumers
        __hip_atomic_fetch_add(cnt, 1u, __ATOMIC_RELAXED, __HIP_MEMORY_SCOPE_AGENT);
    }
  }
}

extern "C" void kernel_launch(void* const* d_in, const int* in_sizes, int n_in,
                              void* d_out, int out_size, void* d_ws, size_t ws_size,
                              hipStream_t stream) {
  (void)in_sizes; (void)n_in; (void)out_size; (void)ws_size;
  const float* x   = (const float*)d_in[0];
  const float* pos = (const float*)d_in[1];
  const float* h0  = (const float*)d_in[2];
  const float* c0  = (const float*)d_in[3];
  const float* Wih = (const float*)d_in[4];
  const float* Whh = (const float*)d_in[5];
  const float* bih = (const float*)d_in[6];
  const float* bhh = (const float*)d_in[7];
  const float* W1  = (const float*)d_in[8];
  const float* b1  = (const float*)d_in[9];
  const float* W2  = (const float*)d_in[10];
  const float* b2  = (const float*)d_in[11];
  const float* W3  = (const float*)d_in[12];
  const float* b3  = (const float*)d_in[13];
  float* out = (float*)d_out;

  hipMemsetAsync(d_ws, 0, 4096, stream);  // group counters

  void* args[] = { (void*)&x, (void*)&pos, (void*)&h0, (void*)&c0,
                   (void*)&Wih, (void*)&Whh, (void*)&bih, (void*)&bhh,
                   (void*)&W1, (void*)&b1, (void*)&W2, (void*)&b2,
                   (void*)&W3, (void*)&b3, (void*)&out, (void*)&d_ws };

  hipError_t err = hipLaunchCooperativeKernel(
      reinterpret_cast<void*>(lstm_persist),
      dim3(256, 1, 1), dim3(256, 1, 1), args, (unsigned)SMEM_BYTES, stream);
  if (err != hipSuccess) {
    (void)hipGetLastError();
    lstm_persist<<<dim3(256, 1, 1), dim3(256, 1, 1), SMEM_BYTES, stream>>>(
        x, pos, h0, c0, Wih, Whh, bih, bhh, W1, b1, W2, b2, W3, b3, out, d_ws);
  }
}